// Round 8
// baseline (547.389 us; speedup 1.0000x reference)
//
#include <hip/hip_runtime.h>
#include <math.h>

#define NN 50000
#define EE 1000000
#define BB 512

__device__ __forceinline__ float sigmoidf_(float x) { return 1.0f / (1.0f + __expf(-x)); }

__device__ __forceinline__ float uload(const float* p) {
    return __uint_as_float(__builtin_amdgcn_readfirstlane(__float_as_uint(*p)));
}
__device__ __forceinline__ int uloadi(const int* p) {
    return __builtin_amdgcn_readfirstlane(*p);
}

// ---------------------------------------------------------------------------
// CSR build: histogram of dst, exclusive scan.
// ---------------------------------------------------------------------------
__global__ __launch_bounds__(256) void hist_kernel(const int* __restrict__ ei,
                                                   int* __restrict__ counts)
{
    int e = blockIdx.x * 256 + threadIdx.x;
    if (e < EE) atomicAdd(&counts[ei[EE + e]], 1);
}

__global__ __launch_bounds__(1024) void scan_kernel(const int* __restrict__ counts,
                                                    int* __restrict__ rowptr,
                                                    int* __restrict__ cursor)
{
    __shared__ int s[1024];
    int t = threadIdx.x;
    const int CH = (NN + 1023) / 1024;
    int lo = t * CH, hi = lo + CH < NN ? lo + CH : NN;
    int sum = 0;
    for (int i = lo; i < hi; ++i) sum += counts[i];
    s[t] = sum;
    __syncthreads();
    for (int off = 1; off < 1024; off <<= 1) {
        int v = (t >= off) ? s[t - off] : 0;
        __syncthreads();
        s[t] += v;
        __syncthreads();
    }
    int base = (t > 0) ? s[t - 1] : 0;
    for (int i = lo; i < hi; ++i) {
        rowptr[i] = base; cursor[i] = base; base += counts[i];
    }
    if (t == 1023) rowptr[NN] = s[1023];
}

// Graph boundaries from the sorted batch array (handles empty graphs).
__global__ __launch_bounds__(256) void batch_bounds_kernel(const int* __restrict__ batch,
                                                           int* __restrict__ brow)
{
    int i = blockIdx.x * 256 + threadIdx.x;
    if (i >= NN) return;
    int bi = batch[i];
    int prev = (i == 0) ? -1 : batch[i - 1];
    for (int v = prev + 1; v <= bi; ++v) brow[v] = i;
    if (i == NN - 1) for (int v = bi + 1; v <= BB; ++v) brow[v] = NN;
}

// Transpose LSTM weights: wihT[k*256+g] = wih[g*128+k], whhT[k*256+g] = whh[g*64+k]
__global__ __launch_bounds__(256) void transpose_w_kernel(const float* __restrict__ wih,
                                                          const float* __restrict__ whh,
                                                          float* __restrict__ wihT,
                                                          float* __restrict__ whhT)
{
    int i = blockIdx.x * 256 + threadIdx.x;
    if (i < 128 * 256) {
        int k = i >> 8, g = i & 255;
        wihT[i] = wih[g * 128 + k];
    } else if (i < 192 * 256) {
        int j = i - 128 * 256;
        int k = j >> 8, g = j & 255;
        whhT[j] = whh[g * 64 + k];
    }
}

// PACKED path: scatter + edge-feature reorder fused.
__global__ __launch_bounds__(256) void scatter_prep_kernel(
    const int* __restrict__ ei, const float* __restrict__ eattr,
    const float* __restrict__ efeat, int* __restrict__ cursor,
    int* __restrict__ srcp, float* __restrict__ ea16)
{
    int e = blockIdx.x * 256 + threadIdx.x;
    if (e >= EE) return;
    int dst = ei[EE + e];
    int pos = atomicAdd(&cursor[dst], 1);
    srcp[pos] = ei[e];
    const float4* pa = reinterpret_cast<const float4*>(eattr) + (size_t)e * 2;
    const float4* pf = reinterpret_cast<const float4*>(efeat) + (size_t)e * 2;
    float4* o = reinterpret_cast<float4*>(ea16 + (size_t)pos * 16);
    o[0] = pa[0]; o[1] = pa[1]; o[2] = pf[0]; o[3] = pf[1];
}

// Fallback path: scatter edge ids only.
__global__ __launch_bounds__(256) void scatter_kernel(const int* __restrict__ ei,
                                                      int* __restrict__ cursor,
                                                      int* __restrict__ perm)
{
    int e = blockIdx.x * 256 + threadIdx.x;
    if (e < EE) {
        int pos = atomicAdd(&cursor[ei[EE + e]], 1);
        perm[pos] = e;
    }
}

// ---------------------------------------------------------------------------
// Fused GINE layer. One wave per node. PACKED: attrs loaded as lane-uniform
// float4s into VGPRs (no readfirstlane, no shfl); only x[src] is a gather.
// ---------------------------------------------------------------------------
template <int CIN, bool PACKED>
__global__ __launch_bounds__(256) void gine_fused_kernel(
    const float* __restrict__ xin, const int* __restrict__ ei,
    const int* __restrict__ pidx,   // PACKED ? srcp : perm
    const int* __restrict__ rowptr,
    const float* __restrict__ eattr, const float* __restrict__ efeat,
    const float* __restrict__ ea16,
    const float* __restrict__ ew, const float* __restrict__ eb,
    const float* __restrict__ w1, const float* __restrict__ b1,
    const float* __restrict__ w2, const float* __restrict__ b2,
    float* __restrict__ hout)
{
    __shared__ float w1_lds[CIN * 64];
    for (int i = threadIdx.x; i < CIN * 64; i += 256) w1_lds[i] = w1[i];
    __syncthreads();

    int wave = threadIdx.x >> 6, lane = threadIdx.x & 63;
    int node = blockIdx.x * 4 + wave;
    if (node >= NN) return;

    int ch = lane & (CIN - 1);

    float wreg[16];
#pragma unroll
    for (int k = 0; k < 16; ++k) wreg[k] = ew[k * CIN + ch];
    float ebv = eb[ch];

    int start = rowptr[node], end = rowptr[node + 1];
    float agg = 0.0f;

    if constexpr (PACKED) {
        if constexpr (CIN == 64) {
            int j = start;
            for (; j + 1 < end; j += 2) {
                const float4* p = reinterpret_cast<const float4*>(ea16) + (size_t)j * 4;
                float a0[16], a1[16];
                *reinterpret_cast<float4*>(&a0[0])  = p[0];
                *reinterpret_cast<float4*>(&a0[4])  = p[1];
                *reinterpret_cast<float4*>(&a0[8])  = p[2];
                *reinterpret_cast<float4*>(&a0[12]) = p[3];
                *reinterpret_cast<float4*>(&a1[0])  = p[4];
                *reinterpret_cast<float4*>(&a1[4])  = p[5];
                *reinterpret_cast<float4*>(&a1[8])  = p[6];
                *reinterpret_cast<float4*>(&a1[12]) = p[7];
                int s0 = pidx[j], s1 = pidx[j + 1];
                float m0 = xin[(size_t)s0 * 64 + lane] + ebv;
                float m1 = xin[(size_t)s1 * 64 + lane] + ebv;
#pragma unroll
                for (int k = 0; k < 16; ++k) {
                    m0 = fmaf(a0[k], wreg[k], m0);
                    m1 = fmaf(a1[k], wreg[k], m1);
                }
                agg += fmaxf(m0, 0.0f) + fmaxf(m1, 0.0f);
            }
            if (j < end) {
                const float4* p = reinterpret_cast<const float4*>(ea16) + (size_t)j * 4;
                float a0[16];
                *reinterpret_cast<float4*>(&a0[0])  = p[0];
                *reinterpret_cast<float4*>(&a0[4])  = p[1];
                *reinterpret_cast<float4*>(&a0[8])  = p[2];
                *reinterpret_cast<float4*>(&a0[12]) = p[3];
                int s0 = pidx[j];
                float m0 = xin[(size_t)s0 * 64 + lane] + ebv;
#pragma unroll
                for (int k = 0; k < 16; ++k) m0 = fmaf(a0[k], wreg[k], m0);
                agg += fmaxf(m0, 0.0f);
            }
        } else {
            // CIN == 32: one edge per half-wave; 4 edges per unrolled iter.
            int half = lane >> 5;
            int j = start;
            for (; j + 3 < end; j += 4) {
                const float4* p0 = reinterpret_cast<const float4*>(ea16) + (size_t)(j + half) * 4;
                const float4* p1 = reinterpret_cast<const float4*>(ea16) + (size_t)(j + 2 + half) * 4;
                float a0[16], a1[16];
                *reinterpret_cast<float4*>(&a0[0])  = p0[0];
                *reinterpret_cast<float4*>(&a0[4])  = p0[1];
                *reinterpret_cast<float4*>(&a0[8])  = p0[2];
                *reinterpret_cast<float4*>(&a0[12]) = p0[3];
                *reinterpret_cast<float4*>(&a1[0])  = p1[0];
                *reinterpret_cast<float4*>(&a1[4])  = p1[1];
                *reinterpret_cast<float4*>(&a1[8])  = p1[2];
                *reinterpret_cast<float4*>(&a1[12]) = p1[3];
                int s0 = pidx[j + half], s1 = pidx[j + 2 + half];
                float m0 = xin[(size_t)s0 * 32 + ch] + ebv;
                float m1 = xin[(size_t)s1 * 32 + ch] + ebv;
#pragma unroll
                for (int k = 0; k < 16; ++k) {
                    m0 = fmaf(a0[k], wreg[k], m0);
                    m1 = fmaf(a1[k], wreg[k], m1);
                }
                agg += fmaxf(m0, 0.0f) + fmaxf(m1, 0.0f);
            }
            for (; j + 1 < end; j += 2) {
                const float4* p0 = reinterpret_cast<const float4*>(ea16) + (size_t)(j + half) * 4;
                float a0[16];
                *reinterpret_cast<float4*>(&a0[0])  = p0[0];
                *reinterpret_cast<float4*>(&a0[4])  = p0[1];
                *reinterpret_cast<float4*>(&a0[8])  = p0[2];
                *reinterpret_cast<float4*>(&a0[12]) = p0[3];
                int s0 = pidx[j + half];
                float m0 = xin[(size_t)s0 * 32 + ch] + ebv;
#pragma unroll
                for (int k = 0; k < 16; ++k) m0 = fmaf(a0[k], wreg[k], m0);
                agg += fmaxf(m0, 0.0f);
            }
            if (j < end) {  // single tail edge: only half 0 contributes
                const float4* p0 = reinterpret_cast<const float4*>(ea16) + (size_t)j * 4;
                float a0[16];
                *reinterpret_cast<float4*>(&a0[0])  = p0[0];
                *reinterpret_cast<float4*>(&a0[4])  = p0[1];
                *reinterpret_cast<float4*>(&a0[8])  = p0[2];
                *reinterpret_cast<float4*>(&a0[12]) = p0[3];
                int s0 = pidx[j];
                float m0 = xin[(size_t)s0 * 32 + ch] + ebv;
#pragma unroll
                for (int k = 0; k < 16; ++k) m0 = fmaf(a0[k], wreg[k], m0);
                agg += (half == 0) ? fmaxf(m0, 0.0f) : 0.0f;
            }
            agg += __shfl_xor(agg, 32);
        }
    } else {
        // Fallback: scalarized loads through perm/ei (R7 path).
        auto fetch16 = [&](int slot, float* a) -> int {
            int e = uloadi(pidx + slot);
            int src = uloadi(ei + e);
            const float* pa = eattr + (size_t)e * 8;
            const float* pf = efeat + (size_t)e * 8;
#pragma unroll
            for (int k = 0; k < 8; ++k) { a[k] = uload(pa + k); a[8 + k] = uload(pf + k); }
            return src;
        };
        for (int j = start; j < end; ++j) {
            int jb = __builtin_amdgcn_readfirstlane(j);
            float a0[16];
            int s0 = fetch16(jb, a0);
            float m0 = xin[(size_t)s0 * CIN + ch] + ebv;
#pragma unroll
            for (int k = 0; k < 16; ++k) m0 = fmaf(a0[k], wreg[k], m0);
            if constexpr (CIN == 64) agg += fmaxf(m0, 0.0f);
            else                      agg += (lane < 32) ? fmaxf(m0, 0.0f) : 0.0f;
        }
    }

    // node MLP (w1 from LDS, w2 from global -- broadcast-hot)
    float h_in = 0.0f;
    if (lane < CIN) h_in = xin[(size_t)node * CIN + lane] + agg;

    float hid = b1[lane];
#pragma unroll
    for (int i = 0; i < CIN; ++i)
        hid += __shfl(h_in, i) * w1_lds[i * 64 + lane];
    hid = fmaxf(hid, 0.0f);

    float o = b2[lane];
#pragma unroll
    for (int i = 0; i < 64; ++i)
        o += __shfl(hid, i) * w2[i * 64 + lane];

    hout[(size_t)node * 64 + lane] = fmaxf(o, 0.0f);
}

// ---------------------------------------------------------------------------
// Set2Set v2: 1024 threads (16 waves) per graph. Transposed LSTM weights for
// coalesced gate reads; e-scores staged in LDS; block-parallel reductions.
// ---------------------------------------------------------------------------
__global__ __launch_bounds__(1024) void set2set_head_v2(
    const float* __restrict__ h2, const int* __restrict__ brow,
    const float* __restrict__ wihT, const float* __restrict__ whhT,
    const float* __restrict__ bih, const float* __restrict__ bhh,
    const float* __restrict__ dw, const float* __restrict__ db,
    const float* __restrict__ ow, const float* __restrict__ ob,
    float* __restrict__ outp)
{
    int b = blockIdx.x, tid = threadIdx.x;
    int wv = tid >> 6, lane = tid & 63;
    __shared__ float qstar[128], hh[64], cc[64];
    __shared__ float gpart[4][256];
    __shared__ float e_lds[2048];
    __shared__ float redw[16][64];
    __shared__ float red1[32];

    int start = brow[b], end = brow[b + 1];
    int nloc = end - start;

    if (tid < 128) qstar[tid] = 0.0f;
    if (tid < 64) { hh[tid] = 0.0f; cc[tid] = 0.0f; }
    __syncthreads();

    float S = 0.0f;  // per-thread copy of the softmax denom (uniform)

    for (int step = 0; step < 3; ++step) {
        // ---- LSTM gates: 4 k-partitions x 256 gates, coalesced wihT/whhT ----
        {
            int p = tid >> 8, g = tid & 255;
            float acc = 0.0f;
            const float* wT = wihT + (size_t)(32 * p) * 256 + g;
#pragma unroll 8
            for (int k = 0; k < 32; ++k) acc += qstar[32 * p + k] * wT[(size_t)k * 256];
            const float* hT = whhT + (size_t)(16 * p) * 256 + g;
#pragma unroll 8
            for (int k = 0; k < 16; ++k) acc += hh[16 * p + k] * hT[(size_t)k * 256];
            gpart[p][g] = acc;
        }
        __syncthreads();
        if (tid < 64) {
            float gi = bih[tid]       + bhh[tid]       + gpart[0][tid]       + gpart[1][tid]       + gpart[2][tid]       + gpart[3][tid];
            float gf = bih[64 + tid]  + bhh[64 + tid]  + gpart[0][64 + tid]  + gpart[1][64 + tid]  + gpart[2][64 + tid]  + gpart[3][64 + tid];
            float gg = bih[128 + tid] + bhh[128 + tid] + gpart[0][128 + tid] + gpart[1][128 + tid] + gpart[2][128 + tid] + gpart[3][128 + tid];
            float go = bih[192 + tid] + bhh[192 + tid] + gpart[0][192 + tid] + gpart[1][192 + tid] + gpart[2][192 + tid] + gpart[3][192 + tid];
            float c = sigmoidf_(gf) * cc[tid] + sigmoidf_(gi) * tanhf(gg);
            cc[tid] = c;
            hh[tid] = sigmoidf_(go) * tanhf(c);
        }
        __syncthreads();

        // ---- attention readout ----
        float qv = hh[lane];
        float M = -INFINITY, racc = 0.0f;
        S = 0.0f;
        for (int base = 0; base < nloc; base += 2048) {
            int cnt = min(nloc - base, 2048);
            // pass 1: e scores
            for (int nl = wv; nl < cnt; nl += 16) {
                float v = h2[(size_t)(start + base + nl) * 64 + lane];
                float pp = v * qv;
#pragma unroll
                for (int off = 32; off; off >>= 1) pp += __shfl_xor(pp, off);
                if (lane == 0) e_lds[nl] = pp;
            }
            __syncthreads();
            // chunk max
            float mx = -INFINITY;
            for (int i2 = tid; i2 < cnt; i2 += 1024) mx = fmaxf(mx, e_lds[i2]);
#pragma unroll
            for (int off = 32; off; off >>= 1) mx = fmaxf(mx, __shfl_xor(mx, off));
            if (lane == 0) red1[wv] = mx;
            __syncthreads();
            if (tid == 0) {
                float m2 = red1[0];
                for (int w2 = 1; w2 < 16; ++w2) m2 = fmaxf(m2, red1[w2]);
                red1[16] = m2;
            }
            __syncthreads();
            float Mc = red1[16];
            float Mn = fmaxf(M, Mc);
            float scale = (M == -INFINITY) ? 0.0f : __expf(M - Mn);
            // chunk denom
            float sm = 0.0f;
            for (int i2 = tid; i2 < cnt; i2 += 1024) sm += __expf(e_lds[i2] - Mn);
#pragma unroll
            for (int off = 32; off; off >>= 1) sm += __shfl_xor(sm, off);
            __syncthreads();
            if (lane == 0) red1[wv] = sm;
            __syncthreads();
            if (tid == 0) {
                float s2 = 0.0f;
                for (int w2 = 0; w2 < 16; ++w2) s2 += red1[w2];
                red1[16] = s2;
            }
            __syncthreads();
            float Sc = red1[16];
            S = S * scale + Sc;
            racc *= scale;
            // pass 2: weighted sum
            for (int nl = wv; nl < cnt; nl += 16) {
                float v = h2[(size_t)(start + base + nl) * 64 + lane];
                racc += __expf(e_lds[nl] - Mn) * v;
            }
            M = Mn;
            __syncthreads();
        }
        redw[wv][lane] = racc;
        __syncthreads();
        if (tid < 64) {
            float r = 0.0f;
#pragma unroll
            for (int w2 = 0; w2 < 16; ++w2) r += redw[w2][tid];
            qstar[tid] = hh[tid];
            qstar[64 + tid] = (S > 0.0f) ? r / S : 0.0f;
        }
        __syncthreads();
    }

    // ---- dense head ----
    if (tid < 64) {
        float z = db[tid];
#pragma unroll 4
        for (int k = 0; k < 128; ++k) z += qstar[k] * dw[k * 64 + tid];
        redw[0][tid] = fmaxf(z, 0.0f);
    }
    __syncthreads();
    if (tid < 64) {
        float t = redw[0][tid] * ow[tid];
#pragma unroll
        for (int off = 32; off; off >>= 1) t += __shfl_xor(t, off);
        if (tid == 0) outp[b] = t + ob[0];
    }
}

// ---------------------------------------------------------------------------
extern "C" void kernel_launch(void* const* d_in, const int* in_sizes, int n_in,
                              void* d_out, int out_size, void* d_ws, size_t ws_size,
                              hipStream_t stream)
{
    const float* x     = (const float*)d_in[0];
    const float* eattr = (const float*)d_in[1];
    const float* efeat = (const float*)d_in[2];
    const int*   ei    = (const int*)d_in[3];
    const int*   batch = (const int*)d_in[4];
    const float* c0_ew = (const float*)d_in[5];  const float* c0_eb = (const float*)d_in[6];
    const float* c0_w1 = (const float*)d_in[7];  const float* c0_b1 = (const float*)d_in[8];
    const float* c0_w2 = (const float*)d_in[9];  const float* c0_b2 = (const float*)d_in[10];
    const float* c1_ew = (const float*)d_in[11]; const float* c1_eb = (const float*)d_in[12];
    const float* c1_w1 = (const float*)d_in[13]; const float* c1_b1 = (const float*)d_in[14];
    const float* c1_w2 = (const float*)d_in[15]; const float* c1_b2 = (const float*)d_in[16];
    const float* wih   = (const float*)d_in[17]; const float* bih   = (const float*)d_in[18];
    const float* whh   = (const float*)d_in[19]; const float* bhh   = (const float*)d_in[20];
    const float* dw    = (const float*)d_in[21]; const float* dbias = (const float*)d_in[22];
    const float* ow    = (const float*)d_in[23]; const float* ob    = (const float*)d_in[24];

    float* out = (float*)d_out;
    int* iws = (int*)d_ws;

    // layout (4B words): counts NN | rowptr NN+1 | cursor NN | brow BB+1 |
    //                    wihT 32768 | whhT 16384 | srcp EE | [align] ea16 16EE | h1 | h2
    int* counts = iws;
    int* rowptr = counts + NN;
    int* cursor = rowptr + NN + 1;
    int* brow   = cursor + NN;
    size_t off0 = ((size_t)3 * NN + 1 + (BB + 1) + 15) & ~(size_t)15;
    float* wihT = (float*)(iws + off0);
    float* whhT = wihT + 128 * 256;
    int*   srcp = (int*)(whhT + 64 * 256);
    size_t offE = (off0 + 128 * 256 + 64 * 256 + EE + 15) & ~(size_t)15;
    float* ea16 = (float*)(iws + offE);
    float* h1   = ea16 + (size_t)EE * 16;
    float* h2   = h1 + (size_t)NN * 64;
    const size_t needP = (offE + (size_t)EE * 16 + (size_t)NN * 128) * sizeof(int);

    hipMemsetAsync(counts, 0, (size_t)NN * sizeof(int), stream);
    hist_kernel<<<(EE + 255) / 256, 256, 0, stream>>>(ei, counts);
    batch_bounds_kernel<<<(NN + 255) / 256, 256, 0, stream>>>(batch, brow);
    transpose_w_kernel<<<192, 256, 0, stream>>>(wih, whh, wihT, whhT);
    scan_kernel<<<1, 1024, 0, stream>>>(counts, rowptr, cursor);

    if (ws_size >= needP) {
        scatter_prep_kernel<<<(EE + 255) / 256, 256, 0, stream>>>(
            ei, eattr, efeat, cursor, srcp, ea16);
        gine_fused_kernel<32, true><<<(NN + 3) / 4, 256, 0, stream>>>(
            x, ei, srcp, rowptr, eattr, efeat, ea16,
            c0_ew, c0_eb, c0_w1, c0_b1, c0_w2, c0_b2, h1);
        gine_fused_kernel<64, true><<<(NN + 3) / 4, 256, 0, stream>>>(
            h1, ei, srcp, rowptr, eattr, efeat, ea16,
            c1_ew, c1_eb, c1_w1, c1_b1, c1_w2, c1_b2, h2);
    } else {
        // Fallback: perm indirection, random feature reads; h1/h2 right after srcp.
        int* perm = srcp;
        float* h1f = (float*)(iws + ((off0 + 128 * 256 + 64 * 256 + EE + 15) & ~(size_t)15));
        float* h2f = h1f + (size_t)NN * 64;
        scatter_kernel<<<(EE + 255) / 256, 256, 0, stream>>>(ei, cursor, perm);
        gine_fused_kernel<32, false><<<(NN + 3) / 4, 256, 0, stream>>>(
            x, ei, perm, rowptr, eattr, efeat, nullptr,
            c0_ew, c0_eb, c0_w1, c0_b1, c0_w2, c0_b2, h1f);
        gine_fused_kernel<64, false><<<(NN + 3) / 4, 256, 0, stream>>>(
            h1f, ei, perm, rowptr, eattr, efeat, nullptr,
            c1_ew, c1_eb, c1_w1, c1_b1, c1_w2, c1_b2, h2f);
        h2 = h2f;
    }

    set2set_head_v2<<<BB, 1024, 0, stream>>>(h2, brow, wihT, whhT, bih, bhh,
                                             dw, dbias, ow, ob, out);
}

// Round 9
// 481.745 us; speedup vs baseline: 1.1363x; 1.1363x over previous
//
#include <hip/hip_runtime.h>
#include <math.h>

#define NN 50000
#define EE 1000000
#define BB 512

__device__ __forceinline__ float sigmoidf_(float x) { return 1.0f / (1.0f + __expf(-x)); }

// Wave-uniform loads: force the value into an SGPR so the attr stream uses the
// scalar memory pipe and dependent FMAs take the scalar operand slot.
__device__ __forceinline__ float uload(const float* p) {
    return __uint_as_float(__builtin_amdgcn_readfirstlane(__float_as_uint(*p)));
}
__device__ __forceinline__ int uloadi(const int* p) {
    return __builtin_amdgcn_readfirstlane(*p);
}

// ---------------------------------------------------------------------------
// CSR build: histogram of dst, exclusive scan.
// ---------------------------------------------------------------------------
__global__ __launch_bounds__(256) void hist_kernel(const int* __restrict__ ei,
                                                   int* __restrict__ counts)
{
    int e = blockIdx.x * 256 + threadIdx.x;
    if (e < EE) atomicAdd(&counts[ei[EE + e]], 1);
}

__global__ __launch_bounds__(1024) void scan_kernel(const int* __restrict__ counts,
                                                    int* __restrict__ rowptr,
                                                    int* __restrict__ cursor)
{
    __shared__ int s[1024];
    int t = threadIdx.x;
    const int CH = (NN + 1023) / 1024;
    int lo = t * CH, hi = lo + CH < NN ? lo + CH : NN;
    int sum = 0;
    for (int i = lo; i < hi; ++i) sum += counts[i];
    s[t] = sum;
    __syncthreads();
    for (int off = 1; off < 1024; off <<= 1) {
        int v = (t >= off) ? s[t - off] : 0;
        __syncthreads();
        s[t] += v;
        __syncthreads();
    }
    int base = (t > 0) ? s[t - 1] : 0;
    for (int i = lo; i < hi; ++i) {
        rowptr[i] = base; cursor[i] = base; base += counts[i];
    }
    if (t == 1023) rowptr[NN] = s[1023];
}

// Graph boundaries from the sorted batch array (handles empty graphs).
__global__ __launch_bounds__(256) void batch_bounds_kernel(const int* __restrict__ batch,
                                                           int* __restrict__ brow)
{
    int i = blockIdx.x * 256 + threadIdx.x;
    if (i >= NN) return;
    int bi = batch[i];
    int prev = (i == 0) ? -1 : batch[i - 1];
    for (int v = prev + 1; v <= bi; ++v) brow[v] = i;
    if (i == NN - 1) for (int v = bi + 1; v <= BB; ++v) brow[v] = NN;
}

// Transpose LSTM weights: wihT[k*256+g] = wih[g*128+k], whhT[k*256+g] = whh[g*64+k]
__global__ __launch_bounds__(256) void transpose_w_kernel(const float* __restrict__ wih,
                                                          const float* __restrict__ whh,
                                                          float* __restrict__ wihT,
                                                          float* __restrict__ whhT)
{
    int i = blockIdx.x * 256 + threadIdx.x;
    if (i < 128 * 256) {
        int k = i >> 8, g = i & 255;
        wihT[i] = wih[g * 128 + k];
    } else if (i < 192 * 256) {
        int j = i - 128 * 256;
        int k = j >> 8, g = j & 255;
        whhT[j] = whh[g * 64 + k];
    }
}

// PACKED path: scatter + edge-feature reorder fused.
__global__ __launch_bounds__(256) void scatter_prep_kernel(
    const int* __restrict__ ei, const float* __restrict__ eattr,
    const float* __restrict__ efeat, int* __restrict__ cursor,
    int* __restrict__ srcp, float* __restrict__ ea16)
{
    int e = blockIdx.x * 256 + threadIdx.x;
    if (e >= EE) return;
    int dst = ei[EE + e];
    int pos = atomicAdd(&cursor[dst], 1);
    srcp[pos] = ei[e];
    const float4* pa = reinterpret_cast<const float4*>(eattr) + (size_t)e * 2;
    const float4* pf = reinterpret_cast<const float4*>(efeat) + (size_t)e * 2;
    float4* o = reinterpret_cast<float4*>(ea16 + (size_t)pos * 16);
    o[0] = pa[0]; o[1] = pa[1]; o[2] = pf[0]; o[3] = pf[1];
}

// Fallback path: scatter edge ids only.
__global__ __launch_bounds__(256) void scatter_kernel(const int* __restrict__ ei,
                                                      int* __restrict__ cursor,
                                                      int* __restrict__ perm)
{
    int e = blockIdx.x * 256 + threadIdx.x;
    if (e < EE) {
        int pos = atomicAdd(&cursor[ei[EE + e]], 1);
        perm[pos] = e;
    }
}

// ---------------------------------------------------------------------------
// Fused GINE layer, scalarized edge loop (R7-proven). One wave per node.
// Per edge: ~16 v_fmac (SGPR x VGPR) + 1 coalesced 256B gather; attrs via
// scalar loads into SGPRs. No DS ops in the edge loop.
// ---------------------------------------------------------------------------
template <int CIN, bool PACKED>
__global__ __launch_bounds__(256) void gine_fused_kernel(
    const float* __restrict__ xin, const int* __restrict__ ei,
    const int* __restrict__ pidx,   // PACKED ? srcp : perm
    const int* __restrict__ rowptr,
    const float* __restrict__ eattr, const float* __restrict__ efeat,
    const float* __restrict__ ea16,
    const float* __restrict__ ew, const float* __restrict__ eb,
    const float* __restrict__ w1, const float* __restrict__ b1,
    const float* __restrict__ w2, const float* __restrict__ b2,
    float* __restrict__ hout)
{
    __shared__ float w1_lds[CIN * 64];
    for (int i = threadIdx.x; i < CIN * 64; i += 256) w1_lds[i] = w1[i];
    __syncthreads();

    int wave = threadIdx.x >> 6, lane = threadIdx.x & 63;
    int node = blockIdx.x * 4 + wave;
    if (node >= NN) return;

    int ch = lane & (CIN - 1);

    float wreg[16];
#pragma unroll
    for (int k = 0; k < 16; ++k) wreg[k] = ew[k * CIN + ch];
    float ebv = eb[ch];

    int start = rowptr[node], end = rowptr[node + 1];
    float agg = 0.0f;

    // fetch 16 edge-attr scalars (SGPRs) + src id for a uniform CSR slot
    auto fetch16 = [&](int slot, float* a) -> int {
        if constexpr (PACKED) {
            int src = uloadi(pidx + slot);
            const float* p = ea16 + (size_t)slot * 16;
#pragma unroll
            for (int k = 0; k < 16; ++k) a[k] = uload(p + k);
            return src;
        } else {
            int e = uloadi(pidx + slot);
            int src = uloadi(ei + e);
            const float* pa = eattr + (size_t)e * 8;
            const float* pf = efeat + (size_t)e * 8;
#pragma unroll
            for (int k = 0; k < 8; ++k) { a[k] = uload(pa + k); a[8 + k] = uload(pf + k); }
            return src;
        }
    };

    if constexpr (CIN == 64) {
        int j = start;
        for (; j + 3 < end; j += 4) {
            int jb = __builtin_amdgcn_readfirstlane(j);
            float a0[16], a1[16], a2[16], a3[16];
            int s0 = fetch16(jb, a0);
            int s1 = fetch16(jb + 1, a1);
            int s2 = fetch16(jb + 2, a2);
            int s3 = fetch16(jb + 3, a3);
            float m0 = xin[(size_t)s0 * 64 + lane] + ebv;
            float m1 = xin[(size_t)s1 * 64 + lane] + ebv;
            float m2 = xin[(size_t)s2 * 64 + lane] + ebv;
            float m3 = xin[(size_t)s3 * 64 + lane] + ebv;
#pragma unroll
            for (int k = 0; k < 16; ++k) {
                m0 += a0[k] * wreg[k];
                m1 += a1[k] * wreg[k];
                m2 += a2[k] * wreg[k];
                m3 += a3[k] * wreg[k];
            }
            agg += fmaxf(m0, 0.0f) + fmaxf(m1, 0.0f)
                 + fmaxf(m2, 0.0f) + fmaxf(m3, 0.0f);
        }
        for (; j < end; ++j) {
            int jb = __builtin_amdgcn_readfirstlane(j);
            float a0[16];
            int s0 = fetch16(jb, a0);
            float m0 = xin[(size_t)s0 * 64 + lane] + ebv;
#pragma unroll
            for (int k = 0; k < 16; ++k) m0 += a0[k] * wreg[k];
            agg += fmaxf(m0, 0.0f);
        }
    } else {
        // CIN == 32: two edges per wave (one per half). Both message sums are
        // computed in all lanes from SGPR operands; per-half select at the end.
        int half = lane >> 5;
        int j = start;
        for (; j + 1 < end; j += 2) {
            int jb = __builtin_amdgcn_readfirstlane(j);
            float a0[16], a1[16];
            int s0 = fetch16(jb, a0);
            int s1 = fetch16(jb + 1, a1);
            float xv = xin[(size_t)(half ? s1 : s0) * 32 + ch];
            float m0 = 0.0f, m1 = 0.0f;
#pragma unroll
            for (int k = 0; k < 16; ++k) {
                m0 += a0[k] * wreg[k];
                m1 += a1[k] * wreg[k];
            }
            float m = half ? m1 : m0;
            agg += fmaxf(xv + m + ebv, 0.0f);
        }
        if (j < end) {  // single tail edge: only half 0 contributes
            int jb = __builtin_amdgcn_readfirstlane(j);
            float a0[16];
            int s0 = fetch16(jb, a0);
            float xv = xin[(size_t)s0 * 32 + ch];
            float m0 = 0.0f;
#pragma unroll
            for (int k = 0; k < 16; ++k) m0 += a0[k] * wreg[k];
            agg += (half == 0) ? fmaxf(xv + m0 + ebv, 0.0f) : 0.0f;
        }
        agg += __shfl_xor(agg, 32);  // combine the two halves
    }

    // node MLP (w1 from LDS, w2 from global -- broadcast-hot)
    float h_in = 0.0f;
    if (lane < CIN) h_in = xin[(size_t)node * CIN + lane] + agg;

    float hid = b1[lane];
#pragma unroll
    for (int i = 0; i < CIN; ++i)
        hid += __shfl(h_in, i) * w1_lds[i * 64 + lane];
    hid = fmaxf(hid, 0.0f);

    float o = b2[lane];
#pragma unroll
    for (int i = 0; i < 64; ++i)
        o += __shfl(hid, i) * w2[i * 64 + lane];

    hout[(size_t)node * 64 + lane] = fmaxf(o, 0.0f);
}

// ---------------------------------------------------------------------------
// Set2Set v2: 1024 threads (16 waves) per graph. Transposed LSTM weights for
// coalesced gate reads; e-scores staged in LDS; block-parallel reductions.
// ---------------------------------------------------------------------------
__global__ __launch_bounds__(1024) void set2set_head_v2(
    const float* __restrict__ h2, const int* __restrict__ brow,
    const float* __restrict__ wihT, const float* __restrict__ whhT,
    const float* __restrict__ bih, const float* __restrict__ bhh,
    const float* __restrict__ dw, const float* __restrict__ db,
    const float* __restrict__ ow, const float* __restrict__ ob,
    float* __restrict__ outp)
{
    int b = blockIdx.x, tid = threadIdx.x;
    int wv = tid >> 6, lane = tid & 63;
    __shared__ float qstar[128], hh[64], cc[64];
    __shared__ float gpart[4][256];
    __shared__ float e_lds[2048];
    __shared__ float redw[16][64];
    __shared__ float red1[32];

    int start = brow[b], end = brow[b + 1];
    int nloc = end - start;

    if (tid < 128) qstar[tid] = 0.0f;
    if (tid < 64) { hh[tid] = 0.0f; cc[tid] = 0.0f; }
    __syncthreads();

    float S = 0.0f;

    for (int step = 0; step < 3; ++step) {
        // ---- LSTM gates: 4 k-partitions x 256 gates, coalesced wihT/whhT ----
        {
            int p = tid >> 8, g = tid & 255;
            float acc = 0.0f;
            const float* wT = wihT + (size_t)(32 * p) * 256 + g;
#pragma unroll 8
            for (int k = 0; k < 32; ++k) acc += qstar[32 * p + k] * wT[(size_t)k * 256];
            const float* hT = whhT + (size_t)(16 * p) * 256 + g;
#pragma unroll 8
            for (int k = 0; k < 16; ++k) acc += hh[16 * p + k] * hT[(size_t)k * 256];
            gpart[p][g] = acc;
        }
        __syncthreads();
        if (tid < 64) {
            float gi = bih[tid]       + bhh[tid]       + gpart[0][tid]       + gpart[1][tid]       + gpart[2][tid]       + gpart[3][tid];
            float gf = bih[64 + tid]  + bhh[64 + tid]  + gpart[0][64 + tid]  + gpart[1][64 + tid]  + gpart[2][64 + tid]  + gpart[3][64 + tid];
            float gg = bih[128 + tid] + bhh[128 + tid] + gpart[0][128 + tid] + gpart[1][128 + tid] + gpart[2][128 + tid] + gpart[3][128 + tid];
            float go = bih[192 + tid] + bhh[192 + tid] + gpart[0][192 + tid] + gpart[1][192 + tid] + gpart[2][192 + tid] + gpart[3][192 + tid];
            float c = sigmoidf_(gf) * cc[tid] + sigmoidf_(gi) * tanhf(gg);
            cc[tid] = c;
            hh[tid] = sigmoidf_(go) * tanhf(c);
        }
        __syncthreads();

        // ---- attention readout ----
        float qv = hh[lane];
        float M = -INFINITY, racc = 0.0f;
        S = 0.0f;
        for (int base = 0; base < nloc; base += 2048) {
            int cnt = min(nloc - base, 2048);
            for (int nl = wv; nl < cnt; nl += 16) {
                float v = h2[(size_t)(start + base + nl) * 64 + lane];
                float pp = v * qv;
#pragma unroll
                for (int off = 32; off; off >>= 1) pp += __shfl_xor(pp, off);
                if (lane == 0) e_lds[nl] = pp;
            }
            __syncthreads();
            float mx = -INFINITY;
            for (int i2 = tid; i2 < cnt; i2 += 1024) mx = fmaxf(mx, e_lds[i2]);
#pragma unroll
            for (int off = 32; off; off >>= 1) mx = fmaxf(mx, __shfl_xor(mx, off));
            if (lane == 0) red1[wv] = mx;
            __syncthreads();
            if (tid == 0) {
                float m2 = red1[0];
                for (int w2 = 1; w2 < 16; ++w2) m2 = fmaxf(m2, red1[w2]);
                red1[16] = m2;
            }
            __syncthreads();
            float Mc = red1[16];
            float Mn = fmaxf(M, Mc);
            float scale = (M == -INFINITY) ? 0.0f : __expf(M - Mn);
            float sm = 0.0f;
            for (int i2 = tid; i2 < cnt; i2 += 1024) sm += __expf(e_lds[i2] - Mn);
#pragma unroll
            for (int off = 32; off; off >>= 1) sm += __shfl_xor(sm, off);
            __syncthreads();
            if (lane == 0) red1[wv] = sm;
            __syncthreads();
            if (tid == 0) {
                float s2 = 0.0f;
                for (int w2 = 0; w2 < 16; ++w2) s2 += red1[w2];
                red1[16] = s2;
            }
            __syncthreads();
            float Sc = red1[16];
            S = S * scale + Sc;
            racc *= scale;
            for (int nl = wv; nl < cnt; nl += 16) {
                float v = h2[(size_t)(start + base + nl) * 64 + lane];
                racc += __expf(e_lds[nl] - Mn) * v;
            }
            M = Mn;
            __syncthreads();
        }
        redw[wv][lane] = racc;
        __syncthreads();
        if (tid < 64) {
            float r = 0.0f;
#pragma unroll
            for (int w2 = 0; w2 < 16; ++w2) r += redw[w2][tid];
            qstar[tid] = hh[tid];
            qstar[64 + tid] = (S > 0.0f) ? r / S : 0.0f;
        }
        __syncthreads();
    }

    // ---- dense head ----
    if (tid < 64) {
        float z = db[tid];
#pragma unroll 4
        for (int k = 0; k < 128; ++k) z += qstar[k] * dw[k * 64 + tid];
        redw[0][tid] = fmaxf(z, 0.0f);
    }
    __syncthreads();
    if (tid < 64) {
        float t = redw[0][tid] * ow[tid];
#pragma unroll
        for (int off = 32; off; off >>= 1) t += __shfl_xor(t, off);
        if (tid == 0) outp[b] = t + ob[0];
    }
}

// ---------------------------------------------------------------------------
extern "C" void kernel_launch(void* const* d_in, const int* in_sizes, int n_in,
                              void* d_out, int out_size, void* d_ws, size_t ws_size,
                              hipStream_t stream)
{
    const float* x     = (const float*)d_in[0];
    const float* eattr = (const float*)d_in[1];
    const float* efeat = (const float*)d_in[2];
    const int*   ei    = (const int*)d_in[3];
    const int*   batch = (const int*)d_in[4];
    const float* c0_ew = (const float*)d_in[5];  const float* c0_eb = (const float*)d_in[6];
    const float* c0_w1 = (const float*)d_in[7];  const float* c0_b1 = (const float*)d_in[8];
    const float* c0_w2 = (const float*)d_in[9];  const float* c0_b2 = (const float*)d_in[10];
    const float* c1_ew = (const float*)d_in[11]; const float* c1_eb = (const float*)d_in[12];
    const float* c1_w1 = (const float*)d_in[13]; const float* c1_b1 = (const float*)d_in[14];
    const float* c1_w2 = (const float*)d_in[15]; const float* c1_b2 = (const float*)d_in[16];
    const float* wih   = (const float*)d_in[17]; const float* bih   = (const float*)d_in[18];
    const float* whh   = (const float*)d_in[19]; const float* bhh   = (const float*)d_in[20];
    const float* dw    = (const float*)d_in[21]; const float* dbias = (const float*)d_in[22];
    const float* ow    = (const float*)d_in[23]; const float* ob    = (const float*)d_in[24];

    float* out = (float*)d_out;
    int* iws = (int*)d_ws;

    // layout (4B words): counts NN | rowptr NN+1 | cursor NN | brow BB+1 |
    //                    wihT 32768 | whhT 16384 | srcp EE | [align] ea16 16EE | h1 | h2
    int* counts = iws;
    int* rowptr = counts + NN;
    int* cursor = rowptr + NN + 1;
    int* brow   = cursor + NN;
    size_t off0 = ((size_t)3 * NN + 1 + (BB + 1) + 15) & ~(size_t)15;
    float* wihT = (float*)(iws + off0);
    float* whhT = wihT + 128 * 256;
    int*   srcp = (int*)(whhT + 64 * 256);
    size_t offE = (off0 + 128 * 256 + 64 * 256 + EE + 15) & ~(size_t)15;
    float* ea16 = (float*)(iws + offE);
    float* h1   = ea16 + (size_t)EE * 16;
    float* h2   = h1 + (size_t)NN * 64;
    const size_t needP = (offE + (size_t)EE * 16 + (size_t)NN * 128) * sizeof(int);

    hipMemsetAsync(counts, 0, (size_t)NN * sizeof(int), stream);
    hist_kernel<<<(EE + 255) / 256, 256, 0, stream>>>(ei, counts);
    batch_bounds_kernel<<<(NN + 255) / 256, 256, 0, stream>>>(batch, brow);
    transpose_w_kernel<<<192, 256, 0, stream>>>(wih, whh, wihT, whhT);
    scan_kernel<<<1, 1024, 0, stream>>>(counts, rowptr, cursor);

    if (ws_size >= needP) {
        scatter_prep_kernel<<<(EE + 255) / 256, 256, 0, stream>>>(
            ei, eattr, efeat, cursor, srcp, ea16);
        gine_fused_kernel<32, true><<<(NN + 3) / 4, 256, 0, stream>>>(
            x, ei, srcp, rowptr, eattr, efeat, ea16,
            c0_ew, c0_eb, c0_w1, c0_b1, c0_w2, c0_b2, h1);
        gine_fused_kernel<64, true><<<(NN + 3) / 4, 256, 0, stream>>>(
            h1, ei, srcp, rowptr, eattr, efeat, ea16,
            c1_ew, c1_eb, c1_w1, c1_b1, c1_w2, c1_b2, h2);
    } else {
        int* perm = srcp;
        float* h1f = (float*)(iws + ((off0 + 128 * 256 + 64 * 256 + EE + 15) & ~(size_t)15));
        float* h2f = h1f + (size_t)NN * 64;
        scatter_kernel<<<(EE + 255) / 256, 256, 0, stream>>>(ei, cursor, perm);
        gine_fused_kernel<32, false><<<(NN + 3) / 4, 256, 0, stream>>>(
            x, ei, perm, rowptr, eattr, efeat, nullptr,
            c0_ew, c0_eb, c0_w1, c0_b1, c0_w2, c0_b2, h1f);
        gine_fused_kernel<64, false><<<(NN + 3) / 4, 256, 0, stream>>>(
            h1f, ei, perm, rowptr, eattr, efeat, nullptr,
            c1_ew, c1_eb, c1_w1, c1_b1, c1_w2, c1_b2, h2f);
        h2 = h2f;
    }

    set2set_head_v2<<<BB, 1024, 0, stream>>>(h2, brow, wihT, whhT, bih, bhh,
                                             dw, dbias, ow, ob, out);
}

// Round 10
// 408.435 us; speedup vs baseline: 1.3402x; 1.1795x over previous
//
#include <hip/hip_runtime.h>
#include <math.h>

#define NN 50000
#define EE 1000000
#define BB 512

__device__ __forceinline__ float sigmoidf_(float x) { return 1.0f / (1.0f + __expf(-x)); }

// Wave-uniform loads: force the value into an SGPR so the attr stream uses the
// scalar memory pipe and dependent FMAs take the scalar operand slot.
__device__ __forceinline__ float uload(const float* p) {
    return __uint_as_float(__builtin_amdgcn_readfirstlane(__float_as_uint(*p)));
}
__device__ __forceinline__ int uloadi(const int* p) {
    return __builtin_amdgcn_readfirstlane(*p);
}

// ---------------------------------------------------------------------------
// CSR build, single atomic pass: rank -> scan -> pack (atomic-free).
// ---------------------------------------------------------------------------
__global__ __launch_bounds__(256) void rank_kernel(const int* __restrict__ ei,
                                                   int* __restrict__ counts,
                                                   int* __restrict__ rnk)
{
    int e = blockIdx.x * 256 + threadIdx.x;
    if (e < EE) rnk[e] = atomicAdd(&counts[ei[EE + e]], 1);
}

__global__ __launch_bounds__(1024) void scan_kernel(const int* __restrict__ counts,
                                                    int* __restrict__ rowptr)
{
    __shared__ int s[1024];
    int t = threadIdx.x;
    const int CH = (NN + 1023) / 1024;
    int lo = t * CH, hi = lo + CH < NN ? lo + CH : NN;
    int sum = 0;
    for (int i = lo; i < hi; ++i) sum += counts[i];
    s[t] = sum;
    __syncthreads();
    for (int off = 1; off < 1024; off <<= 1) {
        int v = (t >= off) ? s[t - off] : 0;
        __syncthreads();
        s[t] += v;
        __syncthreads();
    }
    int base = (t > 0) ? s[t - 1] : 0;
    for (int i = lo; i < hi; ++i) { rowptr[i] = base; base += counts[i]; }
    if (t == 1023) rowptr[NN] = s[1023];
}

// PACKED pack: coalesced attr reads, full-64B-line scattered writes. No atomics.
__global__ __launch_bounds__(256) void pack_kernel(
    const int* __restrict__ ei, const int* __restrict__ rnk,
    const int* __restrict__ rowptr,
    const float* __restrict__ eattr, const float* __restrict__ efeat,
    int* __restrict__ srcp, float* __restrict__ ea16)
{
    int e = blockIdx.x * 256 + threadIdx.x;
    if (e >= EE) return;
    int pos = rowptr[ei[EE + e]] + rnk[e];
    srcp[pos] = ei[e];
    const float4* pa = reinterpret_cast<const float4*>(eattr) + (size_t)e * 2;
    const float4* pf = reinterpret_cast<const float4*>(efeat) + (size_t)e * 2;
    float4* o = reinterpret_cast<float4*>(ea16 + (size_t)pos * 16);
    o[0] = pa[0]; o[1] = pa[1]; o[2] = pf[0]; o[3] = pf[1];
}

// Fallback pack: edge ids only.
__global__ __launch_bounds__(256) void pack_ids_kernel(
    const int* __restrict__ ei, const int* __restrict__ rnk,
    const int* __restrict__ rowptr, int* __restrict__ perm)
{
    int e = blockIdx.x * 256 + threadIdx.x;
    if (e < EE) perm[rowptr[ei[EE + e]] + rnk[e]] = e;
}

// Graph boundaries from the sorted batch array (handles empty graphs).
__global__ __launch_bounds__(256) void batch_bounds_kernel(const int* __restrict__ batch,
                                                           int* __restrict__ brow)
{
    int i = blockIdx.x * 256 + threadIdx.x;
    if (i >= NN) return;
    int bi = batch[i];
    int prev = (i == 0) ? -1 : batch[i - 1];
    for (int v = prev + 1; v <= bi; ++v) brow[v] = i;
    if (i == NN - 1) for (int v = bi + 1; v <= BB; ++v) brow[v] = NN;
}

// Transpose LSTM weights: wihT[k*256+g] = wih[g*128+k], whhT[k*256+g] = whh[g*64+k]
__global__ __launch_bounds__(256) void transpose_w_kernel(const float* __restrict__ wih,
                                                          const float* __restrict__ whh,
                                                          float* __restrict__ wihT,
                                                          float* __restrict__ whhT)
{
    int i = blockIdx.x * 256 + threadIdx.x;
    if (i < 128 * 256) {
        int k = i >> 8, g = i & 255;
        wihT[i] = wih[g * 128 + k];
    } else if (i < 192 * 256) {
        int j = i - 128 * 256;
        int k = j >> 8, g = j & 255;
        whhT[j] = whh[g * 64 + k];
    }
}

// ---------------------------------------------------------------------------
// Fused GINE layer, scalarized edge loop (R7-proven, unchanged). One wave/node.
// ---------------------------------------------------------------------------
template <int CIN, bool PACKED>
__global__ __launch_bounds__(256) void gine_fused_kernel(
    const float* __restrict__ xin, const int* __restrict__ ei,
    const int* __restrict__ pidx,   // PACKED ? srcp : perm
    const int* __restrict__ rowptr,
    const float* __restrict__ eattr, const float* __restrict__ efeat,
    const float* __restrict__ ea16,
    const float* __restrict__ ew, const float* __restrict__ eb,
    const float* __restrict__ w1, const float* __restrict__ b1,
    const float* __restrict__ w2, const float* __restrict__ b2,
    float* __restrict__ hout)
{
    __shared__ float w1_lds[CIN * 64];
    for (int i = threadIdx.x; i < CIN * 64; i += 256) w1_lds[i] = w1[i];
    __syncthreads();

    int wave = threadIdx.x >> 6, lane = threadIdx.x & 63;
    int node = blockIdx.x * 4 + wave;
    if (node >= NN) return;

    int ch = lane & (CIN - 1);

    float wreg[16];
#pragma unroll
    for (int k = 0; k < 16; ++k) wreg[k] = ew[k * CIN + ch];
    float ebv = eb[ch];

    int start = rowptr[node], end = rowptr[node + 1];
    float agg = 0.0f;

    auto fetch16 = [&](int slot, float* a) -> int {
        if constexpr (PACKED) {
            int src = uloadi(pidx + slot);
            const float* p = ea16 + (size_t)slot * 16;
#pragma unroll
            for (int k = 0; k < 16; ++k) a[k] = uload(p + k);
            return src;
        } else {
            int e = uloadi(pidx + slot);
            int src = uloadi(ei + e);
            const float* pa = eattr + (size_t)e * 8;
            const float* pf = efeat + (size_t)e * 8;
#pragma unroll
            for (int k = 0; k < 8; ++k) { a[k] = uload(pa + k); a[8 + k] = uload(pf + k); }
            return src;
        }
    };

    if constexpr (CIN == 64) {
        int j = start;
        for (; j + 3 < end; j += 4) {
            int jb = __builtin_amdgcn_readfirstlane(j);
            float a0[16], a1[16], a2[16], a3[16];
            int s0 = fetch16(jb, a0);
            int s1 = fetch16(jb + 1, a1);
            int s2 = fetch16(jb + 2, a2);
            int s3 = fetch16(jb + 3, a3);
            float m0 = xin[(size_t)s0 * 64 + lane] + ebv;
            float m1 = xin[(size_t)s1 * 64 + lane] + ebv;
            float m2 = xin[(size_t)s2 * 64 + lane] + ebv;
            float m3 = xin[(size_t)s3 * 64 + lane] + ebv;
#pragma unroll
            for (int k = 0; k < 16; ++k) {
                m0 += a0[k] * wreg[k];
                m1 += a1[k] * wreg[k];
                m2 += a2[k] * wreg[k];
                m3 += a3[k] * wreg[k];
            }
            agg += fmaxf(m0, 0.0f) + fmaxf(m1, 0.0f)
                 + fmaxf(m2, 0.0f) + fmaxf(m3, 0.0f);
        }
        for (; j < end; ++j) {
            int jb = __builtin_amdgcn_readfirstlane(j);
            float a0[16];
            int s0 = fetch16(jb, a0);
            float m0 = xin[(size_t)s0 * 64 + lane] + ebv;
#pragma unroll
            for (int k = 0; k < 16; ++k) m0 += a0[k] * wreg[k];
            agg += fmaxf(m0, 0.0f);
        }
    } else {
        int half = lane >> 5;
        int j = start;
        for (; j + 1 < end; j += 2) {
            int jb = __builtin_amdgcn_readfirstlane(j);
            float a0[16], a1[16];
            int s0 = fetch16(jb, a0);
            int s1 = fetch16(jb + 1, a1);
            float xv = xin[(size_t)(half ? s1 : s0) * 32 + ch];
            float m0 = 0.0f, m1 = 0.0f;
#pragma unroll
            for (int k = 0; k < 16; ++k) {
                m0 += a0[k] * wreg[k];
                m1 += a1[k] * wreg[k];
            }
            float m = half ? m1 : m0;
            agg += fmaxf(xv + m + ebv, 0.0f);
        }
        if (j < end) {
            int jb = __builtin_amdgcn_readfirstlane(j);
            float a0[16];
            int s0 = fetch16(jb, a0);
            float xv = xin[(size_t)s0 * 32 + ch];
            float m0 = 0.0f;
#pragma unroll
            for (int k = 0; k < 16; ++k) m0 += a0[k] * wreg[k];
            agg += (half == 0) ? fmaxf(xv + m0 + ebv, 0.0f) : 0.0f;
        }
        agg += __shfl_xor(agg, 32);
    }

    float h_in = 0.0f;
    if (lane < CIN) h_in = xin[(size_t)node * CIN + lane] + agg;

    float hid = b1[lane];
#pragma unroll
    for (int i = 0; i < CIN; ++i)
        hid += __shfl(h_in, i) * w1_lds[i * 64 + lane];
    hid = fmaxf(hid, 0.0f);

    float o = b2[lane];
#pragma unroll
    for (int i = 0; i < 64; ++i)
        o += __shfl(hid, i) * w2[i * 64 + lane];

    hout[(size_t)node * 64 + lane] = fmaxf(o, 0.0f);
}

// ---------------------------------------------------------------------------
// Set2Set v3: single-sweep online softmax per wave, one cross-wave combine.
// 1024 threads (16 waves) per graph; ~4 barriers per step.
// ---------------------------------------------------------------------------
__global__ __launch_bounds__(1024) void set2set_head_v3(
    const float* __restrict__ h2, const int* __restrict__ brow,
    const float* __restrict__ wihT, const float* __restrict__ whhT,
    const float* __restrict__ bih, const float* __restrict__ bhh,
    const float* __restrict__ dw, const float* __restrict__ db,
    const float* __restrict__ ow, const float* __restrict__ ob,
    float* __restrict__ outp)
{
    int b = blockIdx.x, tid = threadIdx.x;
    int wv = tid >> 6, lane = tid & 63;
    __shared__ float qstar[128], hh[64], cc[64];
    __shared__ float gpart[4][256];
    __shared__ float redw[16][64];
    __shared__ float redm[16], reds[16];

    int start = brow[b], end = brow[b + 1];

    if (tid < 128) qstar[tid] = 0.0f;
    if (tid < 64) { hh[tid] = 0.0f; cc[tid] = 0.0f; }
    __syncthreads();

    for (int step = 0; step < 3; ++step) {
        // ---- LSTM gates: 4 k-partitions x 256 gates, coalesced wihT/whhT ----
        {
            int p = tid >> 8, g = tid & 255;
            float acc = 0.0f;
            const float* wT = wihT + (size_t)(32 * p) * 256 + g;
#pragma unroll 8
            for (int k = 0; k < 32; ++k) acc += qstar[32 * p + k] * wT[(size_t)k * 256];
            const float* hT = whhT + (size_t)(16 * p) * 256 + g;
#pragma unroll 8
            for (int k = 0; k < 16; ++k) acc += hh[16 * p + k] * hT[(size_t)k * 256];
            gpart[p][g] = acc;
        }
        __syncthreads();
        if (tid < 64) {
            float gi = bih[tid]       + bhh[tid]       + gpart[0][tid]       + gpart[1][tid]       + gpart[2][tid]       + gpart[3][tid];
            float gf = bih[64 + tid]  + bhh[64 + tid]  + gpart[0][64 + tid]  + gpart[1][64 + tid]  + gpart[2][64 + tid]  + gpart[3][64 + tid];
            float gg = bih[128 + tid] + bhh[128 + tid] + gpart[0][128 + tid] + gpart[1][128 + tid] + gpart[2][128 + tid] + gpart[3][128 + tid];
            float go = bih[192 + tid] + bhh[192 + tid] + gpart[0][192 + tid] + gpart[1][192 + tid] + gpart[2][192 + tid] + gpart[3][192 + tid];
            float c = sigmoidf_(gf) * cc[tid] + sigmoidf_(gi) * tanhf(gg);
            cc[tid] = c;
            hh[tid] = sigmoidf_(go) * tanhf(c);
        }
        __syncthreads();

        // ---- attention readout: one sweep, online (m, s, r) per wave ----
        float qv = hh[lane];
        float mw = -INFINITY, sw = 0.0f, rw = 0.0f;
        for (int n = start + wv; n < end; n += 16) {
            float v = h2[(size_t)n * 64 + lane];
            float p = v * qv;
#pragma unroll
            for (int off = 32; off; off >>= 1) p += __shfl_xor(p, off);
            float nm = fmaxf(mw, p);
            float sc = __expf(mw - nm);         // 0 when mw=-inf, nm finite
            float pe = __expf(p - nm);
            sw = sw * sc + pe;
            rw = rw * sc + pe * v;
            mw = nm;
        }
        redm[wv] = mw; reds[wv] = sw; redw[wv][lane] = rw;
        __syncthreads();
        if (tid < 64) {
            float M = -INFINITY;
#pragma unroll
            for (int w = 0; w < 16; ++w) M = fmaxf(M, redm[w]);
            float S = 0.0f, R = 0.0f;
#pragma unroll
            for (int w = 0; w < 16; ++w) {
                float mm = redm[w];
                if (mm > -INFINITY) {
                    float sc = __expf(mm - M);
                    S += reds[w] * sc;
                    R += redw[w][tid] * sc;
                }
            }
            qstar[tid] = hh[tid];
            qstar[64 + tid] = (S > 0.0f) ? R / S : 0.0f;
        }
        __syncthreads();
    }

    // ---- dense head ----
    if (tid < 64) {
        float z = db[tid];
#pragma unroll 4
        for (int k = 0; k < 128; ++k) z += qstar[k] * dw[k * 64 + tid];
        redw[0][tid] = fmaxf(z, 0.0f);
    }
    __syncthreads();
    if (tid < 64) {
        float t = redw[0][tid] * ow[tid];
#pragma unroll
        for (int off = 32; off; off >>= 1) t += __shfl_xor(t, off);
        if (tid == 0) outp[b] = t + ob[0];
    }
}

// ---------------------------------------------------------------------------
extern "C" void kernel_launch(void* const* d_in, const int* in_sizes, int n_in,
                              void* d_out, int out_size, void* d_ws, size_t ws_size,
                              hipStream_t stream)
{
    const float* x     = (const float*)d_in[0];
    const float* eattr = (const float*)d_in[1];
    const float* efeat = (const float*)d_in[2];
    const int*   ei    = (const int*)d_in[3];
    const int*   batch = (const int*)d_in[4];
    const float* c0_ew = (const float*)d_in[5];  const float* c0_eb = (const float*)d_in[6];
    const float* c0_w1 = (const float*)d_in[7];  const float* c0_b1 = (const float*)d_in[8];
    const float* c0_w2 = (const float*)d_in[9];  const float* c0_b2 = (const float*)d_in[10];
    const float* c1_ew = (const float*)d_in[11]; const float* c1_eb = (const float*)d_in[12];
    const float* c1_w1 = (const float*)d_in[13]; const float* c1_b1 = (const float*)d_in[14];
    const float* c1_w2 = (const float*)d_in[15]; const float* c1_b2 = (const float*)d_in[16];
    const float* wih   = (const float*)d_in[17]; const float* bih   = (const float*)d_in[18];
    const float* whh   = (const float*)d_in[19]; const float* bhh   = (const float*)d_in[20];
    const float* dw    = (const float*)d_in[21]; const float* dbias = (const float*)d_in[22];
    const float* ow    = (const float*)d_in[23]; const float* ob    = (const float*)d_in[24];

    float* out = (float*)d_out;
    int* iws = (int*)d_ws;

    // layout (4B words): counts NN | rowptr NN+1 | brow BB+1 | wihT 32768 |
    //                    whhT 16384 | srcp EE | [align] ea16 16EE | h1 | h2
    // rnk (EE words) aliases h1: pack reads it before gine32 writes h1.
    int* counts = iws;
    int* rowptr = counts + NN;
    int* brow   = rowptr + NN + 1;
    size_t off0 = ((size_t)2 * NN + 1 + (BB + 1) + 15) & ~(size_t)15;
    float* wihT = (float*)(iws + off0);
    float* whhT = wihT + 128 * 256;
    int*   srcp = (int*)(whhT + 64 * 256);
    size_t offE = (off0 + 128 * 256 + 64 * 256 + EE + 15) & ~(size_t)15;
    float* ea16 = (float*)(iws + offE);
    float* h1   = ea16 + (size_t)EE * 16;
    float* h2   = h1 + (size_t)NN * 64;
    int*   rnk  = (int*)h1;     // alias: dead once gine32 runs
    const size_t needP = (offE + (size_t)EE * 16 + (size_t)NN * 128) * sizeof(int);

    hipMemsetAsync(counts, 0, (size_t)NN * sizeof(int), stream);
    batch_bounds_kernel<<<(NN + 255) / 256, 256, 0, stream>>>(batch, brow);
    transpose_w_kernel<<<192, 256, 0, stream>>>(wih, whh, wihT, whhT);

    if (ws_size >= needP) {
        rank_kernel<<<(EE + 255) / 256, 256, 0, stream>>>(ei, counts, rnk);
        scan_kernel<<<1, 1024, 0, stream>>>(counts, rowptr);
        pack_kernel<<<(EE + 255) / 256, 256, 0, stream>>>(
            ei, rnk, rowptr, eattr, efeat, srcp, ea16);
        gine_fused_kernel<32, true><<<(NN + 3) / 4, 256, 0, stream>>>(
            x, ei, srcp, rowptr, eattr, efeat, ea16,
            c0_ew, c0_eb, c0_w1, c0_b1, c0_w2, c0_b2, h1);
        gine_fused_kernel<64, true><<<(NN + 3) / 4, 256, 0, stream>>>(
            h1, ei, srcp, rowptr, eattr, efeat, ea16,
            c1_ew, c1_eb, c1_w1, c1_b1, c1_w2, c1_b2, h2);
    } else {
        // Fallback: perm indirection; rnk aliases the space after perm.
        int* perm = srcp;
        float* h1f = (float*)(iws + offE);
        float* h2f = h1f + (size_t)NN * 64;
        int* rnkf  = (int*)(h2f + (size_t)NN * 64);
        rank_kernel<<<(EE + 255) / 256, 256, 0, stream>>>(ei, counts, rnkf);
        scan_kernel<<<1, 1024, 0, stream>>>(counts, rowptr);
        pack_ids_kernel<<<(EE + 255) / 256, 256, 0, stream>>>(ei, rnkf, rowptr, perm);
        gine_fused_kernel<32, false><<<(NN + 3) / 4, 256, 0, stream>>>(
            x, ei, perm, rowptr, eattr, efeat, nullptr,
            c0_ew, c0_eb, c0_w1, c0_b1, c0_w2, c0_b2, h1f);
        gine_fused_kernel<64, false><<<(NN + 3) / 4, 256, 0, stream>>>(
            h1f, ei, perm, rowptr, eattr, efeat, nullptr,
            c1_ew, c1_eb, c1_w1, c1_b1, c1_w2, c1_b2, h2f);
        h2 = h2f;
    }

    set2set_head_v3<<<BB, 1024, 0, stream>>>(h2, brow, wihT, whhT, bih, bhh,
                                             dw, dbias, ow, ob, out);
}